// Round 1
// baseline (3193.320 us; speedup 1.0000x reference)
//
#include <hip/hip_runtime.h>
#include <cstdint>
#include <cstddef>

#define NN 100000
#define NE 1600000
#define IND 128
#define OUTD 64
#define MDIM 16
#define GHID 64

// ---------------- edge-index dtype detection (int32 vs int64) --------------
__global__ __launch_bounds__(64) void k_detect(const void* ei, int* flag) {
    const unsigned long long* p = (const unsigned long long*)ei;
    int i = threadIdx.x;
    unsigned long long v = p[(size_t)i * (NE / 64)];
    bool hi0 = (v >> 32) == 0ull;
    unsigned long long b = __ballot(hi0);
    if (i == 0) *flag = (b == ~0ull) ? 1 : 0;  // all high dwords zero -> int64
}

__global__ __launch_bounds__(256) void k_convert(const void* ei, const int* flag,
                                                 int* idx32) {
    int i = blockIdx.x * 256 + threadIdx.x;
    if (i >= 2 * NE) return;
    if (*flag)
        idx32[i] = (int)((const long long*)ei)[i];
    else
        idx32[i] = ((const int*)ei)[i];
}

// ---------------- degree init (self-loop weight 1.0) -----------------------
__global__ __launch_bounds__(256) void k_init_deg(float* deg) {
    int n = blockIdx.x * 256 + threadIdx.x;
    if (n < NN) deg[n] = 1.0f;
}

// ---------------- edge gate MLP + degree accumulation ----------------------
__global__ __launch_bounds__(256) void k_gate(
    const float* __restrict__ motif, const int* __restrict__ src,
    const int* __restrict__ dst, const float* __restrict__ w1,
    const float* __restrict__ b1, const float* __restrict__ w2,
    const float* __restrict__ b2, float* __restrict__ gate,
    float* __restrict__ deg) {
    int e = blockIdx.x * 256 + threadIdx.x;
    if (e >= NE) return;
    int s = src[e], d = dst[e];
    float mu[MDIM], mv[MDIM];
    const float4* ms = (const float4*)(motif + (size_t)s * MDIM);
    const float4* mdp = (const float4*)(motif + (size_t)d * MDIM);
#pragma unroll
    for (int q = 0; q < 4; q++) {
        float4 a = ms[q], b = mdp[q];
        mu[4 * q] = a.x; mu[4 * q + 1] = a.y; mu[4 * q + 2] = a.z; mu[4 * q + 3] = a.w;
        mv[4 * q] = b.x; mv[4 * q + 1] = b.y; mv[4 * q + 2] = b.z; mv[4 * q + 3] = b.w;
    }
    float h[GHID];
#pragma unroll
    for (int j = 0; j < GHID; j++) h[j] = b1[j];
    for (int k = 0; k < MDIM; k++) {  // rolled: w1 rows fetched via s_load
        float f0 = mu[k], f1 = mv[k];
        float f2 = fabsf(f0 - f1), f3 = f0 * f1;
#pragma unroll
        for (int j = 0; j < GHID; j++) {
            h[j] = fmaf(f0, w1[k * GHID + j], h[j]);
            h[j] = fmaf(f1, w1[(MDIM + k) * GHID + j], h[j]);
            h[j] = fmaf(f2, w1[(2 * MDIM + k) * GHID + j], h[j]);
            h[j] = fmaf(f3, w1[(3 * MDIM + k) * GHID + j], h[j]);
        }
    }
    float g = b2[0];
#pragma unroll
    for (int j = 0; j < GHID; j++) g = fmaf(fmaxf(h[j], 0.0f), w2[j], g);
    float gt = 1.0f / (1.0f + __expf(-g));
    gate[e] = gt;
    atomicAdd(&deg[d], gt);
}

// ---------------- deg -> deg^-0.5 ------------------------------------------
__global__ __launch_bounds__(256) void k_dinv(float* deg_dinv) {
    int n = blockIdx.x * 256 + threadIdx.x;
    if (n < NN) deg_dinv[n] = rsqrtf(deg_dinv[n]);  // deg >= 1 always
}

// ---------------- xw = A @ W (128x128), hh = xw * dinv^2 -------------------
// block: 256 threads; cg = tid>>5 (0..7) -> cols cg*16..+16 (2 cgs per wave:
// LDS reads 2-way aliased = free). rs = tid&31 -> rows rs*4..+4. 128 rows/blk.
__global__ __launch_bounds__(256) void k_conv_gemm(
    const float* __restrict__ A, const float* __restrict__ Bw,
    const float* __restrict__ dinv, float* __restrict__ xw,
    float* __restrict__ hh) {
    __shared__ float sB[IND * IND];  // 64 KB
    int tid = threadIdx.x;
    {
        const float4* B4 = (const float4*)Bw;
        float4* s4 = (float4*)sB;
#pragma unroll
        for (int i = 0; i < 16; i++) s4[tid + 256 * i] = B4[tid + 256 * i];
    }
    __syncthreads();
    int cg = tid >> 5, rs = tid & 31;
    int row0 = blockIdx.x * 128 + rs * 4;
    int col0 = cg * 16;
    float acc[4][16];
#pragma unroll
    for (int j = 0; j < 4; j++)
#pragma unroll
        for (int c = 0; c < 16; c++) acc[j][c] = 0.0f;
    for (int k = 0; k < IND; k += 4) {
        float4 a[4];
#pragma unroll
        for (int j = 0; j < 4; j++) {
            int r = row0 + j;
            a[j] = (r < NN) ? *(const float4*)(A + (size_t)r * IND + k)
                            : make_float4(0.f, 0.f, 0.f, 0.f);
        }
#pragma unroll
        for (int kk = 0; kk < 4; kk++) {
            float b[16];
            const float4* bb = (const float4*)(sB + (k + kk) * IND + col0);
#pragma unroll
            for (int q = 0; q < 4; q++) {
                float4 t = bb[q];
                b[4 * q] = t.x; b[4 * q + 1] = t.y; b[4 * q + 2] = t.z; b[4 * q + 3] = t.w;
            }
#pragma unroll
            for (int j = 0; j < 4; j++) {
                float av = (kk == 0) ? a[j].x : (kk == 1) ? a[j].y : (kk == 2) ? a[j].z : a[j].w;
#pragma unroll
                for (int c = 0; c < 16; c++) acc[j][c] = fmaf(av, b[c], acc[j][c]);
            }
        }
    }
#pragma unroll
    for (int j = 0; j < 4; j++) {
        int r = row0 + j;
        if (r >= NN) continue;
        float dv = dinv[r];
        float d2 = dv * dv;
        float* xo = xw + (size_t)r * IND + col0;
        float* ho = hh + (size_t)r * IND + col0;
#pragma unroll
        for (int q = 0; q < 4; q++) {
            float4 v = make_float4(acc[j][4 * q], acc[j][4 * q + 1],
                                   acc[j][4 * q + 2], acc[j][4 * q + 3]);
            *(float4*)(xo + 4 * q) = v;
            *(float4*)(ho + 4 * q) =
                make_float4(v.x * d2, v.y * d2, v.z * d2, v.w * d2);
        }
    }
}

// ---------------- scatter: hh[dst] += dinv[s]*gate*dinv[d] * xw[src] -------
// one wave per edge, lane handles channels 2l, 2l+1
__global__ __launch_bounds__(256) void k_scatter(
    const int* __restrict__ src, const int* __restrict__ dst,
    const float* __restrict__ gate, const float* __restrict__ dinv,
    const float* __restrict__ xw, float* __restrict__ hh) {
    int wid = (int)((blockIdx.x * 256 + threadIdx.x) >> 6);
    int lane = threadIdx.x & 63;
    if (wid >= NE) return;
    int s = src[wid], d = dst[wid];
    float nrm = dinv[s] * gate[wid] * dinv[d];
    float2 v = ((const float2*)(xw + (size_t)s * IND))[lane];
    float* hp = hh + (size_t)d * IND + 2 * lane;
    atomicAdd(hp, nrm * v.x);
    atomicAdd(hp + 1, nrm * v.y);
}

// ---------------- LN + relu + residual -------------------------------------
// one wave per node; lane l handles channels l and l+64
__global__ __launch_bounds__(256) void k_ln(
    const float* __restrict__ hh, const float* __restrict__ xold,
    float* __restrict__ xnew, const float* __restrict__ cb,
    const float* __restrict__ lg, const float* __restrict__ lb) {
    int n = blockIdx.x * 4 + (threadIdx.x >> 6);
    int lane = threadIdx.x & 63;
    if (n >= NN) return;
    const float* hr = hh + (size_t)n * IND;
    float v0 = hr[lane] + cb[lane];
    float v1 = hr[64 + lane] + cb[64 + lane];
    float s1 = v0 + v1, s2 = v0 * v0 + v1 * v1;
#pragma unroll
    for (int m = 1; m < 64; m <<= 1) {
        s1 += __shfl_xor(s1, m, 64);
        s2 += __shfl_xor(s2, m, 64);
    }
    float mean = s1 * (1.0f / 128.0f);
    float var = s2 * (1.0f / 128.0f) - mean * mean;
    float rs = rsqrtf(var + 1e-5f);
    float y0 = fmaxf((v0 - mean) * rs * lg[lane] + lb[lane], 0.0f);
    float y1 = fmaxf((v1 - mean) * rs * lg[64 + lane] + lb[64 + lane], 0.0f);
    xnew[(size_t)n * IND + lane] = xold[(size_t)n * IND + lane] + y0;
    xnew[(size_t)n * IND + 64 + lane] = xold[(size_t)n * IND + 64 + lane] + y1;
}

// ---------------- head: out = A @ head_w + head_b --------------------------
// cg = tid>>6 (wave-uniform -> LDS broadcast), rs = tid&63 -> 2 rows each
__global__ __launch_bounds__(256) void k_head(
    const float* __restrict__ A, const float* __restrict__ Bw,
    const float* __restrict__ bias, float* __restrict__ out) {
    __shared__ float sB[IND * OUTD];  // 32 KB
    int tid = threadIdx.x;
    {
        const float4* B4 = (const float4*)Bw;
        float4* s4 = (float4*)sB;
#pragma unroll
        for (int i = 0; i < 8; i++) s4[tid + 256 * i] = B4[tid + 256 * i];
    }
    __syncthreads();
    int cg = tid >> 6, rs = tid & 63;
    int row0 = blockIdx.x * 128 + rs * 2;
    int col0 = cg * 16;
    float acc[2][16];
#pragma unroll
    for (int j = 0; j < 2; j++)
#pragma unroll
        for (int c = 0; c < 16; c++) acc[j][c] = 0.0f;
    for (int k = 0; k < IND; k += 4) {
        float4 a[2];
#pragma unroll
        for (int j = 0; j < 2; j++) {
            int r = row0 + j;
            a[j] = (r < NN) ? *(const float4*)(A + (size_t)r * IND + k)
                            : make_float4(0.f, 0.f, 0.f, 0.f);
        }
#pragma unroll
        for (int kk = 0; kk < 4; kk++) {
            float b[16];
            const float4* bb = (const float4*)(sB + (k + kk) * OUTD + col0);
#pragma unroll
            for (int q = 0; q < 4; q++) {
                float4 t = bb[q];
                b[4 * q] = t.x; b[4 * q + 1] = t.y; b[4 * q + 2] = t.z; b[4 * q + 3] = t.w;
            }
#pragma unroll
            for (int j = 0; j < 2; j++) {
                float av = (kk == 0) ? a[j].x : (kk == 1) ? a[j].y : (kk == 2) ? a[j].z : a[j].w;
#pragma unroll
                for (int c = 0; c < 16; c++) acc[j][c] = fmaf(av, b[c], acc[j][c]);
            }
        }
    }
#pragma unroll
    for (int j = 0; j < 2; j++) {
        int r = row0 + j;
        if (r >= NN) continue;
        float* op = out + (size_t)r * OUTD + col0;
#pragma unroll
        for (int q = 0; q < 4; q++) {
            float4 bs = *(const float4*)(bias + col0 + 4 * q);
            *(float4*)(op + 4 * q) =
                make_float4(acc[j][4 * q] + bs.x, acc[j][4 * q + 1] + bs.y,
                            acc[j][4 * q + 2] + bs.z, acc[j][4 * q + 3] + bs.w);
        }
    }
}

extern "C" void kernel_launch(void* const* d_in, const int* in_sizes, int n_in,
                              void* d_out, int out_size, void* d_ws,
                              size_t ws_size, hipStream_t stream) {
    const float* x = (const float*)d_in[0];
    const float* motif = (const float*)d_in[1];
    const void* ei = d_in[2];
    const float* gw1 = (const float*)d_in[3];
    const float* gb1 = (const float*)d_in[4];
    const float* gw2 = (const float*)d_in[5];
    const float* gb2 = (const float*)d_in[6];
    const float* cw = (const float*)d_in[7];   // [2,128,128]
    const float* cb = (const float*)d_in[8];   // [2,128]
    const float* lg = (const float*)d_in[9];
    const float* lb = (const float*)d_in[10];
    const float* hw = (const float*)d_in[11];  // [128,64]
    const float* hb = (const float*)d_in[12];
    float* out = (float*)d_out;

    float* ws = (float*)d_ws;
    size_t o = 0;
    float* gate = ws + o; o += NE;
    float* dinv = ws + o; o += NN;
    int* idx32 = (int*)(ws + o); o += 2 * (size_t)NE;
    int* flag = (int*)(ws + o); o += 64;
    float* xw = ws + o; o += (size_t)NN * IND;
    float* hh = ws + o; o += (size_t)NN * IND;
    float* xc = ws + o; o += (size_t)NN * IND;

    const int* src = idx32;
    const int* dst = idx32 + NE;

    k_detect<<<1, 64, 0, stream>>>(ei, flag);
    k_convert<<<(2 * NE + 255) / 256, 256, 0, stream>>>(ei, flag, idx32);
    k_init_deg<<<(NN + 255) / 256, 256, 0, stream>>>(dinv);
    k_gate<<<NE / 256, 256, 0, stream>>>(motif, src, dst, gw1, gb1, gw2, gb2,
                                         gate, dinv);
    k_dinv<<<(NN + 255) / 256, 256, 0, stream>>>(dinv);

    // layer 0
    k_conv_gemm<<<(NN + 127) / 128, 256, 0, stream>>>(x, cw, dinv, xw, hh);
    k_scatter<<<NE / 4, 256, 0, stream>>>(src, dst, gate, dinv, xw, hh);
    k_ln<<<(NN + 3) / 4, 256, 0, stream>>>(hh, x, xc, cb, lg, lb);

    // layer 1
    k_conv_gemm<<<(NN + 127) / 128, 256, 0, stream>>>(xc, cw + IND * IND, dinv,
                                                      xw, hh);
    k_scatter<<<NE / 4, 256, 0, stream>>>(src, dst, gate, dinv, xw, hh);
    k_ln<<<(NN + 3) / 4, 256, 0, stream>>>(hh, xc, xc, cb + IND, lg + IND,
                                           lb + IND);

    k_head<<<(NN + 127) / 128, 256, 0, stream>>>(xc, hw, hb, out);
}

// Round 2
// 913.737 us; speedup vs baseline: 3.4948x; 3.4948x over previous
//
#include <hip/hip_runtime.h>
#include <cstdint>
#include <cstddef>

#define NN 100000
#define NE 1600000
#define IND 128
#define OUTD 64
#define MDIM 16
#define GHID 64

// ---------------- edge-index dtype detection (int32 vs int64) --------------
__global__ __launch_bounds__(64) void k_detect(const void* ei, int* flag) {
    const unsigned long long* p = (const unsigned long long*)ei;
    int i = threadIdx.x;
    unsigned long long v = p[(size_t)i * (NE / 64)];
    bool hi0 = (v >> 32) == 0ull;
    unsigned long long b = __ballot(hi0);
    if (i == 0) *flag = (b == ~0ull) ? 1 : 0;  // all high dwords zero -> int64
}

__global__ __launch_bounds__(256) void k_convert(const void* ei, const int* flag,
                                                 int* idx32) {
    int i = blockIdx.x * 256 + threadIdx.x;
    if (i >= 2 * NE) return;
    if (*flag)
        idx32[i] = (int)((const long long*)ei)[i];
    else
        idx32[i] = ((const int*)ei)[i];
}

// ---------------- degree init (self-loop weight 1.0) + count zero ----------
__global__ __launch_bounds__(256) void k_init(float* deg, int* count) {
    int n = blockIdx.x * 256 + threadIdx.x;
    if (n < NN) { deg[n] = 1.0f; count[n] = 0; }
}

// ---------------- edge gate MLP + degree accumulation + dst histogram ------
__global__ __launch_bounds__(256) void k_gate(
    const float* __restrict__ motif, const int* __restrict__ src,
    const int* __restrict__ dst, const float* __restrict__ w1,
    const float* __restrict__ b1, const float* __restrict__ w2,
    const float* __restrict__ b2, float* __restrict__ gate,
    float* __restrict__ deg, int* __restrict__ count) {
    int e = blockIdx.x * 256 + threadIdx.x;
    if (e >= NE) return;
    int s = src[e], d = dst[e];
    float mu[MDIM], mv[MDIM];
    const float4* ms = (const float4*)(motif + (size_t)s * MDIM);
    const float4* mdp = (const float4*)(motif + (size_t)d * MDIM);
#pragma unroll
    for (int q = 0; q < 4; q++) {
        float4 a = ms[q], b = mdp[q];
        mu[4 * q] = a.x; mu[4 * q + 1] = a.y; mu[4 * q + 2] = a.z; mu[4 * q + 3] = a.w;
        mv[4 * q] = b.x; mv[4 * q + 1] = b.y; mv[4 * q + 2] = b.z; mv[4 * q + 3] = b.w;
    }
    float h[GHID];
#pragma unroll
    for (int j = 0; j < GHID; j++) h[j] = b1[j];
    for (int k = 0; k < MDIM; k++) {  // rolled: w1 rows fetched via s_load
        float f0 = mu[k], f1 = mv[k];
        float f2 = fabsf(f0 - f1), f3 = f0 * f1;
#pragma unroll
        for (int j = 0; j < GHID; j++) {
            h[j] = fmaf(f0, w1[k * GHID + j], h[j]);
            h[j] = fmaf(f1, w1[(MDIM + k) * GHID + j], h[j]);
            h[j] = fmaf(f2, w1[(2 * MDIM + k) * GHID + j], h[j]);
            h[j] = fmaf(f3, w1[(3 * MDIM + k) * GHID + j], h[j]);
        }
    }
    float g = b2[0];
#pragma unroll
    for (int j = 0; j < GHID; j++) g = fmaf(fmaxf(h[j], 0.0f), w2[j], g);
    float gt = 1.0f / (1.0f + __expf(-g));
    gate[e] = gt;
    atomicAdd(&deg[d], gt);
    atomicAdd(&count[d], 1);
}

// ---------------- deg -> deg^-0.5 ------------------------------------------
__global__ __launch_bounds__(256) void k_dinv(float* deg_dinv) {
    int n = blockIdx.x * 256 + threadIdx.x;
    if (n < NN) deg_dinv[n] = rsqrtf(deg_dinv[n]);  // deg >= 1 always
}

// ---------------- counting-sort scan (exclusive prefix of count) -----------
// pass 1: 2048 elements per block (256 thr x 8)
__global__ __launch_bounds__(256) void k_scan1(const int* __restrict__ count,
                                               int* __restrict__ rs,
                                               int* __restrict__ bsum) {
    __shared__ int sd[256];
    int tid = threadIdx.x;
    int base = blockIdx.x * 2048 + tid * 8;
    int loc[8]; int s = 0;
#pragma unroll
    for (int i = 0; i < 8; i++) {
        int idx = base + i;
        int v = (idx < NN) ? count[idx] : 0;
        loc[i] = s; s += v;
    }
    sd[tid] = s; __syncthreads();
    for (int off = 1; off < 256; off <<= 1) {
        int t = (tid >= off) ? sd[tid - off] : 0;
        __syncthreads();
        sd[tid] += t;
        __syncthreads();
    }
    int texcl = sd[tid] - s;
    if (tid == 255) bsum[blockIdx.x] = sd[255];
#pragma unroll
    for (int i = 0; i < 8; i++) {
        int idx = base + i;
        if (idx < NN) rs[idx] = texcl + loc[i];
    }
}

// pass 2: single wave scans the 49 block sums
__global__ __launch_bounds__(64) void k_scan2(const int* __restrict__ bsum,
                                              int* __restrict__ boffs) {
    int tid = threadIdx.x;
    int v = (tid < 49) ? bsum[tid] : 0;
    int x = v;
#pragma unroll
    for (int off = 1; off < 64; off <<= 1) {
        int t = __shfl_up(x, off, 64);
        if (tid >= off) x += t;
    }
    boffs[tid] = x - v;  // exclusive
}

// pass 3: add block offsets; init cursor
__global__ __launch_bounds__(256) void k_scan3(int* __restrict__ rs,
                                               const int* __restrict__ boffs,
                                               int* __restrict__ cursor) {
    int i = blockIdx.x * 256 + threadIdx.x;
    if (i < NN) {
        int v = rs[i] + boffs[i >> 11];
        rs[i] = v;
        cursor[i] = v;
    }
}

// ---------------- fill CSR: src + precomputed edge weight, sorted by dst ---
__global__ __launch_bounds__(256) void k_fill(
    const int* __restrict__ src, const int* __restrict__ dst,
    const float* __restrict__ gate, const float* __restrict__ dinv,
    int* __restrict__ cursor, int* __restrict__ src_s,
    float* __restrict__ w_s) {
    int e = blockIdx.x * 256 + threadIdx.x;
    if (e >= NE) return;
    int s = src[e], d = dst[e];
    int pos = atomicAdd(&cursor[d], 1);
    src_s[pos] = s;
    w_s[pos] = dinv[s] * gate[e] * dinv[d];
}

// ---------------- xw = A @ W (128x128) -------------------------------------
__global__ __launch_bounds__(256) void k_conv_gemm(
    const float* __restrict__ A, const float* __restrict__ Bw,
    float* __restrict__ xw) {
    __shared__ float sB[IND * IND];  // 64 KB
    int tid = threadIdx.x;
    {
        const float4* B4 = (const float4*)Bw;
        float4* s4 = (float4*)sB;
#pragma unroll
        for (int i = 0; i < 16; i++) s4[tid + 256 * i] = B4[tid + 256 * i];
    }
    __syncthreads();
    int cg = tid >> 5, rs = tid & 31;
    int row0 = blockIdx.x * 128 + rs * 4;
    int col0 = cg * 16;
    float acc[4][16];
#pragma unroll
    for (int j = 0; j < 4; j++)
#pragma unroll
        for (int c = 0; c < 16; c++) acc[j][c] = 0.0f;
    for (int k = 0; k < IND; k += 4) {
        float4 a[4];
#pragma unroll
        for (int j = 0; j < 4; j++) {
            int r = row0 + j;
            a[j] = (r < NN) ? *(const float4*)(A + (size_t)r * IND + k)
                            : make_float4(0.f, 0.f, 0.f, 0.f);
        }
#pragma unroll
        for (int kk = 0; kk < 4; kk++) {
            float b[16];
            const float4* bb = (const float4*)(sB + (k + kk) * IND + col0);
#pragma unroll
            for (int q = 0; q < 4; q++) {
                float4 t = bb[q];
                b[4 * q] = t.x; b[4 * q + 1] = t.y; b[4 * q + 2] = t.z; b[4 * q + 3] = t.w;
            }
#pragma unroll
            for (int j = 0; j < 4; j++) {
                float av = (kk == 0) ? a[j].x : (kk == 1) ? a[j].y : (kk == 2) ? a[j].z : a[j].w;
#pragma unroll
                for (int c = 0; c < 16; c++) acc[j][c] = fmaf(av, b[c], acc[j][c]);
            }
        }
    }
#pragma unroll
    for (int j = 0; j < 4; j++) {
        int r = row0 + j;
        if (r >= NN) continue;
        float* xo = xw + (size_t)r * IND + col0;
#pragma unroll
        for (int q = 0; q < 4; q++)
            *(float4*)(xo + 4 * q) =
                make_float4(acc[j][4 * q], acc[j][4 * q + 1], acc[j][4 * q + 2],
                            acc[j][4 * q + 3]);
    }
}

// ---------------- fused gather + bias + LN + relu + residual ---------------
// one wave per node; lane l handles channels 2l, 2l+1 (float2)
__global__ __launch_bounds__(256) void k_aggr(
    const int* __restrict__ rowstart, const int* __restrict__ count,
    const int* __restrict__ src_s, const float* __restrict__ w_s,
    const float* __restrict__ xw, const float* __restrict__ dinv,
    const float* __restrict__ xold, float* __restrict__ xnew,
    const float* __restrict__ cb, const float* __restrict__ lg,
    const float* __restrict__ lb) {
    int n = blockIdx.x * 4 + (threadIdx.x >> 6);
    int lane = threadIdx.x & 63;
    if (n >= NN) return;
    const float2* xw2 = (const float2*)xw;
    float dn = dinv[n];
    float2 acc = xw2[(size_t)n * 64 + lane];  // self-loop: dinv[n]^2 * xw[n]
    acc.x *= dn * dn; acc.y *= dn * dn;
    int start = rowstart[n], cnt = count[n];
    for (int c = 0; c < cnt; c += 64) {
        int rem = cnt - c;
        int sv = 0; float wv = 0.0f;
        if (lane < rem) {
            sv = src_s[start + c + lane];
            wv = w_s[start + c + lane];
        }
        int m = rem < 64 ? rem : 64;
        int j = 0;
        for (; j + 4 <= m; j += 4) {  // 4 independent loads in flight
            int s0 = __shfl(sv, j, 64), s1 = __shfl(sv, j + 1, 64);
            int s2 = __shfl(sv, j + 2, 64), s3 = __shfl(sv, j + 3, 64);
            float w0 = __shfl(wv, j, 64), w1 = __shfl(wv, j + 1, 64);
            float w2 = __shfl(wv, j + 2, 64), w3 = __shfl(wv, j + 3, 64);
            float2 v0 = xw2[(size_t)s0 * 64 + lane];
            float2 v1 = xw2[(size_t)s1 * 64 + lane];
            float2 v2 = xw2[(size_t)s2 * 64 + lane];
            float2 v3 = xw2[(size_t)s3 * 64 + lane];
            acc.x = fmaf(w0, v0.x, acc.x); acc.y = fmaf(w0, v0.y, acc.y);
            acc.x = fmaf(w1, v1.x, acc.x); acc.y = fmaf(w1, v1.y, acc.y);
            acc.x = fmaf(w2, v2.x, acc.x); acc.y = fmaf(w2, v2.y, acc.y);
            acc.x = fmaf(w3, v3.x, acc.x); acc.y = fmaf(w3, v3.y, acc.y);
        }
        for (; j < m; j++) {
            int s = __shfl(sv, j, 64);
            float w = __shfl(wv, j, 64);
            float2 v = xw2[(size_t)s * 64 + lane];
            acc.x = fmaf(w, v.x, acc.x); acc.y = fmaf(w, v.y, acc.y);
        }
    }
    float2 cbv = ((const float2*)cb)[lane];
    acc.x += cbv.x; acc.y += cbv.y;
    float s1 = acc.x + acc.y, s2 = acc.x * acc.x + acc.y * acc.y;
#pragma unroll
    for (int mm = 1; mm < 64; mm <<= 1) {
        s1 += __shfl_xor(s1, mm, 64);
        s2 += __shfl_xor(s2, mm, 64);
    }
    float mean = s1 * (1.0f / 128.0f);
    float var = s2 * (1.0f / 128.0f) - mean * mean;
    float rstd = rsqrtf(var + 1e-5f);
    float2 lgv = ((const float2*)lg)[lane];
    float2 lbv = ((const float2*)lb)[lane];
    float y0 = fmaxf((acc.x - mean) * rstd * lgv.x + lbv.x, 0.0f);
    float y1 = fmaxf((acc.y - mean) * rstd * lgv.y + lbv.y, 0.0f);
    float2 xo = ((const float2*)xold)[(size_t)n * 64 + lane];
    ((float2*)xnew)[(size_t)n * 64 + lane] =
        make_float2(xo.x + y0, xo.y + y1);
}

// ---------------- head: out = A @ head_w + head_b --------------------------
__global__ __launch_bounds__(256) void k_head(
    const float* __restrict__ A, const float* __restrict__ Bw,
    const float* __restrict__ bias, float* __restrict__ out) {
    __shared__ float sB[IND * OUTD];  // 32 KB
    int tid = threadIdx.x;
    {
        const float4* B4 = (const float4*)Bw;
        float4* s4 = (float4*)sB;
#pragma unroll
        for (int i = 0; i < 8; i++) s4[tid + 256 * i] = B4[tid + 256 * i];
    }
    __syncthreads();
    int cg = tid >> 6, rs = tid & 63;
    int row0 = blockIdx.x * 128 + rs * 2;
    int col0 = cg * 16;
    float acc[2][16];
#pragma unroll
    for (int j = 0; j < 2; j++)
#pragma unroll
        for (int c = 0; c < 16; c++) acc[j][c] = 0.0f;
    for (int k = 0; k < IND; k += 4) {
        float4 a[2];
#pragma unroll
        for (int j = 0; j < 2; j++) {
            int r = row0 + j;
            a[j] = (r < NN) ? *(const float4*)(A + (size_t)r * IND + k)
                            : make_float4(0.f, 0.f, 0.f, 0.f);
        }
#pragma unroll
        for (int kk = 0; kk < 4; kk++) {
            float b[16];
            const float4* bb = (const float4*)(sB + (k + kk) * OUTD + col0);
#pragma unroll
            for (int q = 0; q < 4; q++) {
                float4 t = bb[q];
                b[4 * q] = t.x; b[4 * q + 1] = t.y; b[4 * q + 2] = t.z; b[4 * q + 3] = t.w;
            }
#pragma unroll
            for (int j = 0; j < 2; j++) {
                float av = (kk == 0) ? a[j].x : (kk == 1) ? a[j].y : (kk == 2) ? a[j].z : a[j].w;
#pragma unroll
                for (int c = 0; c < 16; c++) acc[j][c] = fmaf(av, b[c], acc[j][c]);
            }
        }
    }
#pragma unroll
    for (int j = 0; j < 2; j++) {
        int r = row0 + j;
        if (r >= NN) continue;
        float* op = out + (size_t)r * OUTD + col0;
#pragma unroll
        for (int q = 0; q < 4; q++) {
            float4 bs = *(const float4*)(bias + col0 + 4 * q);
            *(float4*)(op + 4 * q) =
                make_float4(acc[j][4 * q] + bs.x, acc[j][4 * q + 1] + bs.y,
                            acc[j][4 * q + 2] + bs.z, acc[j][4 * q + 3] + bs.w);
        }
    }
}

extern "C" void kernel_launch(void* const* d_in, const int* in_sizes, int n_in,
                              void* d_out, int out_size, void* d_ws,
                              size_t ws_size, hipStream_t stream) {
    const float* x = (const float*)d_in[0];
    const float* motif = (const float*)d_in[1];
    const void* ei = d_in[2];
    const float* gw1 = (const float*)d_in[3];
    const float* gb1 = (const float*)d_in[4];
    const float* gw2 = (const float*)d_in[5];
    const float* gb2 = (const float*)d_in[6];
    const float* cw = (const float*)d_in[7];   // [2,128,128]
    const float* cb = (const float*)d_in[8];   // [2,128]
    const float* lg = (const float*)d_in[9];
    const float* lb = (const float*)d_in[10];
    const float* hw = (const float*)d_in[11];  // [128,64]
    const float* hb = (const float*)d_in[12];
    float* out = (float*)d_out;

    float* ws = (float*)d_ws;
    size_t o = 0;
    float* gate = ws + o; o += NE;
    float* dinv = ws + o; o += NN;
    int* idx32 = (int*)(ws + o); o += 2 * (size_t)NE;
    int* flag = (int*)(ws + o); o += 64;
    int* count = (int*)(ws + o); o += NN;
    int* rowstart = (int*)(ws + o); o += NN;
    int* cursor = (int*)(ws + o); o += NN;
    int* bsum = (int*)(ws + o); o += 64;
    int* boffs = (int*)(ws + o); o += 64;
    int* src_s = (int*)(ws + o); o += NE;
    float* w_s = ws + o; o += NE;
    float* xw = ws + o; o += (size_t)NN * IND;
    float* xc = ws + o; o += (size_t)NN * IND;

    const int* src = idx32;
    const int* dst = idx32 + NE;

    k_detect<<<1, 64, 0, stream>>>(ei, flag);
    k_convert<<<(2 * NE + 255) / 256, 256, 0, stream>>>(ei, flag, idx32);
    k_init<<<(NN + 255) / 256, 256, 0, stream>>>(dinv, count);
    k_gate<<<NE / 256, 256, 0, stream>>>(motif, src, dst, gw1, gb1, gw2, gb2,
                                         gate, dinv, count);
    k_dinv<<<(NN + 255) / 256, 256, 0, stream>>>(dinv);

    // counting sort by dst -> CSR (shared by both layers)
    k_scan1<<<(NN + 2047) / 2048, 256, 0, stream>>>(count, rowstart, bsum);
    k_scan2<<<1, 64, 0, stream>>>(bsum, boffs);
    k_scan3<<<(NN + 255) / 256, 256, 0, stream>>>(rowstart, boffs, cursor);
    k_fill<<<NE / 256, 256, 0, stream>>>(src, dst, gate, dinv, cursor, src_s,
                                         w_s);

    // layer 0
    k_conv_gemm<<<(NN + 127) / 128, 256, 0, stream>>>(x, cw, xw);
    k_aggr<<<(NN + 3) / 4, 256, 0, stream>>>(rowstart, count, src_s, w_s, xw,
                                             dinv, x, xc, cb, lg, lb);
    // layer 1
    k_conv_gemm<<<(NN + 127) / 128, 256, 0, stream>>>(xc, cw + IND * IND, xw);
    k_aggr<<<(NN + 3) / 4, 256, 0, stream>>>(rowstart, count, src_s, w_s, xw,
                                             dinv, xc, xc, cb + IND, lg + IND,
                                             lb + IND);

    k_head<<<(NN + 127) / 128, 256, 0, stream>>>(xc, hw, hb, out);
}

// Round 3
// 902.703 us; speedup vs baseline: 3.5375x; 1.0122x over previous
//
#include <hip/hip_runtime.h>
#include <cstdint>
#include <cstddef>

#define NN 100000
#define NE 1600000
#define IND 128
#define OUTD 64
#define MDIM 16
#define GHID 64

// ---------------- edge-index dtype detection (int32 vs int64) --------------
__global__ __launch_bounds__(64) void k_detect(const void* ei, int* flag) {
    const unsigned long long* p = (const unsigned long long*)ei;
    int i = threadIdx.x;
    unsigned long long v = p[(size_t)i * (NE / 64)];
    bool hi0 = (v >> 32) == 0ull;
    unsigned long long b = __ballot(hi0);
    if (i == 0) *flag = (b == ~0ull) ? 1 : 0;  // all high dwords zero -> int64
}

__global__ __launch_bounds__(256) void k_convert(const void* ei, const int* flag,
                                                 int* idx32) {
    int i = blockIdx.x * 256 + threadIdx.x;
    if (i >= 2 * NE) return;
    if (*flag)
        idx32[i] = (int)((const long long*)ei)[i];
    else
        idx32[i] = ((const int*)ei)[i];
}

// ---------------- degree init (self-loop weight 1.0) + count zero ----------
__global__ __launch_bounds__(256) void k_init(float* deg, int* count) {
    int n = blockIdx.x * 256 + threadIdx.x;
    if (n < NN) { deg[n] = 1.0f; count[n] = 0; }
}

// ---------------- edge gate MLP + degree accumulation + dst histogram ------
// Two j-half passes keep live floats ~= mu16+mv16+h32 < 128 VGPR: no scratch
// spill (round-2 version spilled: VGPR_Count=56 with ~100 live, 160MB scratch
// traffic). W1 rows arrive via wave-uniform s_loads feeding v_fmac.
__global__ __launch_bounds__(256) void k_gate(
    const float* __restrict__ motif, const int* __restrict__ src,
    const int* __restrict__ dst, const float* __restrict__ w1,
    const float* __restrict__ b1, const float* __restrict__ w2,
    const float* __restrict__ b2, float* __restrict__ gate,
    float* __restrict__ deg, int* __restrict__ count) {
    int e = blockIdx.x * 256 + threadIdx.x;
    if (e >= NE) return;
    int s = src[e], d = dst[e];
    float mu[MDIM], mv[MDIM];
    const float4* ms = (const float4*)(motif + (size_t)s * MDIM);
    const float4* mdp = (const float4*)(motif + (size_t)d * MDIM);
#pragma unroll
    for (int q = 0; q < 4; q++) {
        float4 a = ms[q], b = mdp[q];
        mu[4 * q] = a.x; mu[4 * q + 1] = a.y; mu[4 * q + 2] = a.z; mu[4 * q + 3] = a.w;
        mv[4 * q] = b.x; mv[4 * q + 1] = b.y; mv[4 * q + 2] = b.z; mv[4 * q + 3] = b.w;
    }
    float g = b2[0];
#pragma unroll 1
    for (int jh = 0; jh < 2; jh++) {
        const float* w1p = w1 + jh * 32;
        const float* b1p = b1 + jh * 32;
        const float* w2p = w2 + jh * 32;
        float h[32];
#pragma unroll
        for (int j = 0; j < 32; j++) h[j] = b1p[j];
#pragma unroll 1
        for (int k = 0; k < MDIM; k++) {
            float f0 = mu[k], f1 = mv[k];
            float f2 = fabsf(f0 - f1), f3 = f0 * f1;
            const float* w = w1p + k * GHID;
#pragma unroll
            for (int j = 0; j < 32; j++) {
                h[j] = fmaf(f0, w[j], h[j]);
                h[j] = fmaf(f1, w[MDIM * GHID + j], h[j]);
                h[j] = fmaf(f2, w[2 * MDIM * GHID + j], h[j]);
                h[j] = fmaf(f3, w[3 * MDIM * GHID + j], h[j]);
            }
        }
#pragma unroll
        for (int j = 0; j < 32; j++) g = fmaf(fmaxf(h[j], 0.0f), w2p[j], g);
    }
    float gt = 1.0f / (1.0f + __expf(-g));
    gate[e] = gt;
    atomicAdd(&deg[d], gt);
    atomicAdd(&count[d], 1);
}

// ---------------- deg -> deg^-0.5 ------------------------------------------
__global__ __launch_bounds__(256) void k_dinv(float* deg_dinv) {
    int n = blockIdx.x * 256 + threadIdx.x;
    if (n < NN) deg_dinv[n] = rsqrtf(deg_dinv[n]);  // deg >= 1 always
}

// ---------------- counting-sort scan (exclusive prefix of count) -----------
// pass 1: 2048 elements per block (256 thr x 8)
__global__ __launch_bounds__(256) void k_scan1(const int* __restrict__ count,
                                               int* __restrict__ rs,
                                               int* __restrict__ bsum) {
    __shared__ int sd[256];
    int tid = threadIdx.x;
    int base = blockIdx.x * 2048 + tid * 8;
    int loc[8]; int s = 0;
#pragma unroll
    for (int i = 0; i < 8; i++) {
        int idx = base + i;
        int v = (idx < NN) ? count[idx] : 0;
        loc[i] = s; s += v;
    }
    sd[tid] = s; __syncthreads();
    for (int off = 1; off < 256; off <<= 1) {
        int t = (tid >= off) ? sd[tid - off] : 0;
        __syncthreads();
        sd[tid] += t;
        __syncthreads();
    }
    int texcl = sd[tid] - s;
    if (tid == 255) bsum[blockIdx.x] = sd[255];
#pragma unroll
    for (int i = 0; i < 8; i++) {
        int idx = base + i;
        if (idx < NN) rs[idx] = texcl + loc[i];
    }
}

// pass 2: single wave scans the 49 block sums
__global__ __launch_bounds__(64) void k_scan2(const int* __restrict__ bsum,
                                              int* __restrict__ boffs) {
    int tid = threadIdx.x;
    int v = (tid < 49) ? bsum[tid] : 0;
    int x = v;
#pragma unroll
    for (int off = 1; off < 64; off <<= 1) {
        int t = __shfl_up(x, off, 64);
        if (tid >= off) x += t;
    }
    boffs[tid] = x - v;  // exclusive
}

// pass 3: add block offsets; init cursor
__global__ __launch_bounds__(256) void k_scan3(int* __restrict__ rs,
                                               const int* __restrict__ boffs,
                                               int* __restrict__ cursor) {
    int i = blockIdx.x * 256 + threadIdx.x;
    if (i < NN) {
        int v = rs[i] + boffs[i >> 11];
        rs[i] = v;
        cursor[i] = v;
    }
}

// ---------------- fill CSR: src + precomputed edge weight, sorted by dst ---
__global__ __launch_bounds__(256) void k_fill(
    const int* __restrict__ src, const int* __restrict__ dst,
    const float* __restrict__ gate, const float* __restrict__ dinv,
    int* __restrict__ cursor, int* __restrict__ src_s,
    float* __restrict__ w_s) {
    int e = blockIdx.x * 256 + threadIdx.x;
    if (e >= NE) return;
    int s = src[e], d = dst[e];
    int pos = atomicAdd(&cursor[d], 1);
    src_s[pos] = s;
    w_s[pos] = dinv[s] * gate[e] * dinv[d];
}

// ---------------- xw = A @ W (128x128) -------------------------------------
__global__ __launch_bounds__(256) void k_conv_gemm(
    const float* __restrict__ A, const float* __restrict__ Bw,
    float* __restrict__ xw) {
    __shared__ float sB[IND * IND];  // 64 KB
    int tid = threadIdx.x;
    {
        const float4* B4 = (const float4*)Bw;
        float4* s4 = (float4*)sB;
#pragma unroll
        for (int i = 0; i < 16; i++) s4[tid + 256 * i] = B4[tid + 256 * i];
    }
    __syncthreads();
    int cg = tid >> 5, rs = tid & 31;
    int row0 = blockIdx.x * 128 + rs * 4;
    int col0 = cg * 16;
    float acc[4][16];
#pragma unroll
    for (int j = 0; j < 4; j++)
#pragma unroll
        for (int c = 0; c < 16; c++) acc[j][c] = 0.0f;
    for (int k = 0; k < IND; k += 4) {
        float4 a[4];
#pragma unroll
        for (int j = 0; j < 4; j++) {
            int r = row0 + j;
            a[j] = (r < NN) ? *(const float4*)(A + (size_t)r * IND + k)
                            : make_float4(0.f, 0.f, 0.f, 0.f);
        }
#pragma unroll
        for (int kk = 0; kk < 4; kk++) {
            float b[16];
            const float4* bb = (const float4*)(sB + (k + kk) * IND + col0);
#pragma unroll
            for (int q = 0; q < 4; q++) {
                float4 t = bb[q];
                b[4 * q] = t.x; b[4 * q + 1] = t.y; b[4 * q + 2] = t.z; b[4 * q + 3] = t.w;
            }
#pragma unroll
            for (int j = 0; j < 4; j++) {
                float av = (kk == 0) ? a[j].x : (kk == 1) ? a[j].y : (kk == 2) ? a[j].z : a[j].w;
#pragma unroll
                for (int c = 0; c < 16; c++) acc[j][c] = fmaf(av, b[c], acc[j][c]);
            }
        }
    }
#pragma unroll
    for (int j = 0; j < 4; j++) {
        int r = row0 + j;
        if (r >= NN) continue;
        float* xo = xw + (size_t)r * IND + col0;
#pragma unroll
        for (int q = 0; q < 4; q++)
            *(float4*)(xo + 4 * q) =
                make_float4(acc[j][4 * q], acc[j][4 * q + 1], acc[j][4 * q + 2],
                            acc[j][4 * q + 3]);
    }
}

// ---------------- fused gather + bias + LN + relu + residual ---------------
// one wave per node; lane l handles channels 2l, 2l+1 (float2)
__global__ __launch_bounds__(256) void k_aggr(
    const int* __restrict__ rowstart, const int* __restrict__ count,
    const int* __restrict__ src_s, const float* __restrict__ w_s,
    const float* __restrict__ xw, const float* __restrict__ dinv,
    const float* __restrict__ xold, float* __restrict__ xnew,
    const float* __restrict__ cb, const float* __restrict__ lg,
    const float* __restrict__ lb) {
    int n = blockIdx.x * 4 + (threadIdx.x >> 6);
    int lane = threadIdx.x & 63;
    if (n >= NN) return;
    const float2* xw2 = (const float2*)xw;
    float dn = dinv[n];
    float2 acc = xw2[(size_t)n * 64 + lane];  // self-loop: dinv[n]^2 * xw[n]
    acc.x *= dn * dn; acc.y *= dn * dn;
    int start = rowstart[n], cnt = count[n];
    for (int c = 0; c < cnt; c += 64) {
        int rem = cnt - c;
        int sv = 0; float wv = 0.0f;
        if (lane < rem) {
            sv = src_s[start + c + lane];
            wv = w_s[start + c + lane];
        }
        int m = rem < 64 ? rem : 64;
        int j = 0;
        for (; j + 4 <= m; j += 4) {  // 4 independent loads in flight
            int s0 = __shfl(sv, j, 64), s1 = __shfl(sv, j + 1, 64);
            int s2 = __shfl(sv, j + 2, 64), s3 = __shfl(sv, j + 3, 64);
            float w0 = __shfl(wv, j, 64), w1 = __shfl(wv, j + 1, 64);
            float w2 = __shfl(wv, j + 2, 64), w3 = __shfl(wv, j + 3, 64);
            float2 v0 = xw2[(size_t)s0 * 64 + lane];
            float2 v1 = xw2[(size_t)s1 * 64 + lane];
            float2 v2 = xw2[(size_t)s2 * 64 + lane];
            float2 v3 = xw2[(size_t)s3 * 64 + lane];
            acc.x = fmaf(w0, v0.x, acc.x); acc.y = fmaf(w0, v0.y, acc.y);
            acc.x = fmaf(w1, v1.x, acc.x); acc.y = fmaf(w1, v1.y, acc.y);
            acc.x = fmaf(w2, v2.x, acc.x); acc.y = fmaf(w2, v2.y, acc.y);
            acc.x = fmaf(w3, v3.x, acc.x); acc.y = fmaf(w3, v3.y, acc.y);
        }
        for (; j < m; j++) {
            int s = __shfl(sv, j, 64);
            float w = __shfl(wv, j, 64);
            float2 v = xw2[(size_t)s * 64 + lane];
            acc.x = fmaf(w, v.x, acc.x); acc.y = fmaf(w, v.y, acc.y);
        }
    }
    float2 cbv = ((const float2*)cb)[lane];
    acc.x += cbv.x; acc.y += cbv.y;
    float s1 = acc.x + acc.y, s2 = acc.x * acc.x + acc.y * acc.y;
#pragma unroll
    for (int mm = 1; mm < 64; mm <<= 1) {
        s1 += __shfl_xor(s1, mm, 64);
        s2 += __shfl_xor(s2, mm, 64);
    }
    float mean = s1 * (1.0f / 128.0f);
    float var = s2 * (1.0f / 128.0f) - mean * mean;
    float rstd = rsqrtf(var + 1e-5f);
    float2 lgv = ((const float2*)lg)[lane];
    float2 lbv = ((const float2*)lb)[lane];
    float y0 = fmaxf((acc.x - mean) * rstd * lgv.x + lbv.x, 0.0f);
    float y1 = fmaxf((acc.y - mean) * rstd * lgv.y + lbv.y, 0.0f);
    float2 xo = ((const float2*)xold)[(size_t)n * 64 + lane];
    ((float2*)xnew)[(size_t)n * 64 + lane] =
        make_float2(xo.x + y0, xo.y + y1);
}

// ---------------- head: out = A @ head_w + head_b --------------------------
__global__ __launch_bounds__(256) void k_head(
    const float* __restrict__ A, const float* __restrict__ Bw,
    const float* __restrict__ bias, float* __restrict__ out) {
    __shared__ float sB[IND * OUTD];  // 32 KB
    int tid = threadIdx.x;
    {
        const float4* B4 = (const float4*)Bw;
        float4* s4 = (float4*)sB;
#pragma unroll
        for (int i = 0; i < 8; i++) s4[tid + 256 * i] = B4[tid + 256 * i];
    }
    __syncthreads();
    int cg = tid >> 6, rs = tid & 63;
    int row0 = blockIdx.x * 128 + rs * 2;
    int col0 = cg * 16;
    float acc[2][16];
#pragma unroll
    for (int j = 0; j < 2; j++)
#pragma unroll
        for (int c = 0; c < 16; c++) acc[j][c] = 0.0f;
    for (int k = 0; k < IND; k += 4) {
        float4 a[2];
#pragma unroll
        for (int j = 0; j < 2; j++) {
            int r = row0 + j;
            a[j] = (r < NN) ? *(const float4*)(A + (size_t)r * IND + k)
                            : make_float4(0.f, 0.f, 0.f, 0.f);
        }
#pragma unroll
        for (int kk = 0; kk < 4; kk++) {
            float b[16];
            const float4* bb = (const float4*)(sB + (k + kk) * OUTD + col0);
#pragma unroll
            for (int q = 0; q < 4; q++) {
                float4 t = bb[q];
                b[4 * q] = t.x; b[4 * q + 1] = t.y; b[4 * q + 2] = t.z; b[4 * q + 3] = t.w;
            }
#pragma unroll
            for (int j = 0; j < 2; j++) {
                float av = (kk == 0) ? a[j].x : (kk == 1) ? a[j].y : (kk == 2) ? a[j].z : a[j].w;
#pragma unroll
                for (int c = 0; c < 16; c++) acc[j][c] = fmaf(av, b[c], acc[j][c]);
            }
        }
    }
#pragma unroll
    for (int j = 0; j < 2; j++) {
        int r = row0 + j;
        if (r >= NN) continue;
        float* op = out + (size_t)r * OUTD + col0;
#pragma unroll
        for (int q = 0; q < 4; q++) {
            float4 bs = *(const float4*)(bias + col0 + 4 * q);
            *(float4*)(op + 4 * q) =
                make_float4(acc[j][4 * q] + bs.x, acc[j][4 * q + 1] + bs.y,
                            acc[j][4 * q + 2] + bs.z, acc[j][4 * q + 3] + bs.w);
        }
    }
}

extern "C" void kernel_launch(void* const* d_in, const int* in_sizes, int n_in,
                              void* d_out, int out_size, void* d_ws,
                              size_t ws_size, hipStream_t stream) {
    const float* x = (const float*)d_in[0];
    const float* motif = (const float*)d_in[1];
    const void* ei = d_in[2];
    const float* gw1 = (const float*)d_in[3];
    const float* gb1 = (const float*)d_in[4];
    const float* gw2 = (const float*)d_in[5];
    const float* gb2 = (const float*)d_in[6];
    const float* cw = (const float*)d_in[7];   // [2,128,128]
    const float* cb = (const float*)d_in[8];   // [2,128]
    const float* lg = (const float*)d_in[9];
    const float* lb = (const float*)d_in[10];
    const float* hw = (const float*)d_in[11];  // [128,64]
    const float* hb = (const float*)d_in[12];
    float* out = (float*)d_out;

    float* ws = (float*)d_ws;
    size_t o = 0;
    float* gate = ws + o; o += NE;
    float* dinv = ws + o; o += NN;
    int* idx32 = (int*)(ws + o); o += 2 * (size_t)NE;
    int* flag = (int*)(ws + o); o += 64;
    int* count = (int*)(ws + o); o += NN;
    int* rowstart = (int*)(ws + o); o += NN;
    int* cursor = (int*)(ws + o); o += NN;
    int* bsum = (int*)(ws + o); o += 64;
    int* boffs = (int*)(ws + o); o += 64;
    int* src_s = (int*)(ws + o); o += NE;
    float* w_s = ws + o; o += NE;
    float* xw = ws + o; o += (size_t)NN * IND;
    float* xc = ws + o; o += (size_t)NN * IND;

    const int* src = idx32;
    const int* dst = idx32 + NE;

    k_detect<<<1, 64, 0, stream>>>(ei, flag);
    k_convert<<<(2 * NE + 255) / 256, 256, 0, stream>>>(ei, flag, idx32);
    k_init<<<(NN + 255) / 256, 256, 0, stream>>>(dinv, count);
    k_gate<<<NE / 256, 256, 0, stream>>>(motif, src, dst, gw1, gb1, gw2, gb2,
                                         gate, dinv, count);
    k_dinv<<<(NN + 255) / 256, 256, 0, stream>>>(dinv);

    // counting sort by dst -> CSR (shared by both layers)
    k_scan1<<<(NN + 2047) / 2048, 256, 0, stream>>>(count, rowstart, bsum);
    k_scan2<<<1, 64, 0, stream>>>(bsum, boffs);
    k_scan3<<<(NN + 255) / 256, 256, 0, stream>>>(rowstart, boffs, cursor);
    k_fill<<<NE / 256, 256, 0, stream>>>(src, dst, gate, dinv, cursor, src_s,
                                         w_s);

    // layer 0
    k_conv_gemm<<<(NN + 127) / 128, 256, 0, stream>>>(x, cw, xw);
    k_aggr<<<(NN + 3) / 4, 256, 0, stream>>>(rowstart, count, src_s, w_s, xw,
                                             dinv, x, xc, cb, lg, lb);
    // layer 1
    k_conv_gemm<<<(NN + 127) / 128, 256, 0, stream>>>(xc, cw + IND * IND, xw);
    k_aggr<<<(NN + 3) / 4, 256, 0, stream>>>(rowstart, count, src_s, w_s, xw,
                                             dinv, xc, xc, cb + IND, lg + IND,
                                             lb + IND);

    k_head<<<(NN + 127) / 128, 256, 0, stream>>>(xc, hw, hb, out);
}